// Round 4
// baseline (330.212 us; speedup 1.0000x reference)
//
#include <hip/hip_runtime.h>
#include <math.h>

typedef float f4 __attribute__((ext_vector_type(4)));

#define GEPS 1e-6f

// ---------------------------------------------------------------------------
// Kernel 1: per-speaker prep.
// block n (1024 blocks, 256 thr). Computes:
//   cent_t[d][n]  (transposed centroid matrix, for kernel2's [d][k] staging)
//   cn[n]   = ||cent_n||
//   xn[n,m] = ||x_{n,m}||
//   dsim[n,m] = cos-sim(x_{n,m}, mod_cent_{n,m})  with eps clamp
// ---------------------------------------------------------------------------
__global__ __launch_bounds__(256) void k1_prep(
    const float* __restrict__ x, float* __restrict__ cent_t,
    float* __restrict__ cn, float* __restrict__ xn, float* __restrict__ dsim)
{
  const int n = blockIdx.x;
  const int tid = threadIdx.x;
  const int lane = tid & 63;
  const int wv = tid >> 6;
  __shared__ float xl[32 * 256];   // x[n] tile
  __shared__ float sl[256];        // sum over m per d
  __shared__ float red[4];

  const float* xg = x + (size_t)n * 8192;
  float s = 0.f;
  #pragma unroll
  for (int m = 0; m < 32; ++m) {
    float v = xg[m * 256 + tid];   // coalesced: 256 consecutive floats per m
    xl[m * 256 + tid] = v;
    s += v;
  }
  sl[tid] = s;
  const float c = s * 0.03125f;               // mean over M=32 (exact, pow2)
  cent_t[(size_t)tid * 1024 + n] = c;         // scatter write (transposed)

  // cent_norm: block reduction of c^2
  float c2 = c * c;
  #pragma unroll
  for (int off = 32; off; off >>= 1) c2 += __shfl_xor(c2, off, 64);
  if (lane == 0) red[wv] = c2;
  __syncthreads();                 // also publishes xl, sl
  if (tid == 0) cn[n] = sqrtf(red[0] + red[1] + red[2] + red[3]);

  // per-m stats: wave wv handles m = wv, wv+4, ..., wv+28
  #pragma unroll
  for (int g = 0; g < 8; ++g) {
    const int m = wv + 4 * g;
    float a1 = 0.f, a2 = 0.f, a3 = 0.f;
    #pragma unroll
    for (int e = 0; e < 4; ++e) {
      const int d = lane + 64 * e;
      const float xv = xl[m * 256 + d];
      const float mo = (sl[d] - xv) / 31.0f;   // mod_cent element
      a1 += xv * xv;
      a2 += xv * mo;
      a3 += mo * mo;
    }
    #pragma unroll
    for (int off = 32; off; off >>= 1) {
      a1 += __shfl_xor(a1, off, 64);
      a2 += __shfl_xor(a2, off, 64);
      a3 += __shfl_xor(a3, off, 64);
    }
    if (lane == 0) {
      const float xnv = sqrtf(a1);
      const float mn  = sqrtf(a3);
      xn[n * 32 + m]   = xnv;
      dsim[n * 32 + m] = a2 / fmaxf(xnv * mn, GEPS);
    }
  }
}

// ---------------------------------------------------------------------------
// Kernel 2: fused dots-GEMM + partial sum-exp with fixed bound B=|w|+|b|.
// grid 4096 = 1024 n x 4 k-slabs (256 k each). 256 thr: lane=tk (4 k each),
// wave=tm (8 m rows each). x[n] (32KiB) + cent chunk [32d][256k] (32KiB) LDS.
// Adds  sum_j exp(w*sim+b-B)  per row into row_sum[n,m] (atomic, 4 adds/row).
// Since |sim|<=1, calc-B = w*sim+b-|w|-|b| is in [-2|w|-2|b|, 0]: the fixed
// bound makes cross-block partial sums combinable with no online max, and is
// mathematically identical to max-subtracted LSE (no overflow; exp(-30) is
// a normal fp32).
// Pipe budget (theory): per d0-step/wave 128 FMA = 256 VALU cyc vs ~4.25 KiB
// LDS reads; x8 waves/CU = 34 KiB -> 272 cyc at 128 B/cyc/CU < 512 cyc VALU
// wall -> VALU-bound, LDS ~53%.
// ---------------------------------------------------------------------------
__global__ __launch_bounds__(256, 2) void k2_gemm_lse(
    const float* __restrict__ x, const float* __restrict__ cent_t,
    const float* __restrict__ cn, const float* __restrict__ xn,
    const float* __restrict__ dsim, const float* __restrict__ wp,
    const float* __restrict__ bp, float* __restrict__ row_sum)
{
  const int bid = blockIdx.x;
  const int n = bid >> 2;
  const int kbase = (bid & 3) << 8;
  const int tid = threadIdx.x;
  const int lane = tid & 63;
  const int wv = tid >> 6;
  __shared__ float xl[32 * 256];
  __shared__ float cl[32 * 256];   // cent chunk, [d-local][k-local] layout

  // stage x[n] -> LDS (plain coalesced float4 copy, once)
  {
    const float* xg = x + (size_t)n * 8192;
    #pragma unroll
    for (int t = 0; t < 8; ++t) {
      f4 v = *(const f4*)(xg + t * 1024 + tid * 4);
      *(f4*)&xl[t * 1024 + tid * 4] = v;
    }
  }

  const float w = wp[0], b = bp[0];
  const float B = fabsf(w) + fabsf(b);
  float cnv[4], xnv[8];
  #pragma unroll
  for (int j = 0; j < 4; ++j) cnv[j] = cn[kbase + lane * 4 + j];
  #pragma unroll
  for (int i = 0; i < 8; ++i) xnv[i] = xn[n * 32 + wv * 8 + i];

  float acc[8][4];
  #pragma unroll
  for (int i = 0; i < 8; ++i)
    #pragma unroll
    for (int j = 0; j < 4; ++j) acc[i][j] = 0.f;

  for (int cc = 0; cc < 8; ++cc) {            // 8 d-chunks of 32
    __syncthreads();   // prev compute done before overwriting cl (and xl ready)
    // stage cent chunk: wave wv loads rows wv*8..wv*8+7, 1 KiB per issue
    // (global_load_lds: LDS dest is wave-uniform base + lane*16 -> row r of
    //  cl gets cent_t[cc*32+r][kbase + lane*4 .. +3] exactly as laid out)
    #pragma unroll
    for (int i = 0; i < 8; ++i) {
      const int r = wv * 8 + i;
      const float* src = cent_t + (size_t)(cc * 32 + r) * 1024 + kbase + lane * 4;
      float* dst = &cl[r * 256];              // wave-uniform base
      __builtin_amdgcn_global_load_lds(
          (const __attribute__((address_space(1))) void*)src,
          (__attribute__((address_space(3))) void*)dst, 16, 0, 0);
    }
    __syncthreads();   // compiler drains vmcnt(0) before s_barrier -> staged
    const int dbase = cc * 32;
    #pragma unroll 2
    for (int d0 = 0; d0 < 32; d0 += 4) {
      f4 cv[4];
      #pragma unroll
      for (int dd = 0; dd < 4; ++dd)          // conflict-free: lane-stride 16B
        cv[dd] = *(const f4*)&cl[(d0 + dd) * 256 + lane * 4];
      f4 av[8];
      #pragma unroll
      for (int i = 0; i < 8; ++i)             // broadcast: wave-uniform addr
        av[i] = *(const f4*)&xl[(wv * 8 + i) * 256 + dbase + d0];
      #pragma unroll
      for (int i = 0; i < 8; ++i)
        #pragma unroll
        for (int dd = 0; dd < 4; ++dd)
          #pragma unroll
          for (int j = 0; j < 4; ++j)
            acc[i][j] = fmaf(av[i][dd], cv[dd][j], acc[i][j]);
    }
  }

  // epilogue: sim -> exp(calc - B) -> per-row wave reduce -> atomic
  #pragma unroll
  for (int i = 0; i < 8; ++i) {
    const int row = n * 32 + wv * 8 + i;
    float p = 0.f;
    #pragma unroll
    for (int j = 0; j < 4; ++j) {
      const int kg = kbase + lane * 4 + j;
      const float denom = fmaxf(xnv[i] * cnv[j], GEPS);
      float sim = acc[i][j] / denom;
      if (kg == n) sim = dsim[row];           // diagonal: modified centroid
      p += __expf(fmaf(w, sim, b) - B);
    }
    #pragma unroll
    for (int off = 32; off; off >>= 1) p += __shfl_xor(p, off, 64);
    if (lane == 0) atomicAdd(&row_sum[row], p);
  }
}

// ---------------------------------------------------------------------------
// Kernel 3: loss_i = -(w*dsim+b) + B + log(row_sum), summed into d_out.
// ---------------------------------------------------------------------------
__global__ __launch_bounds__(256) void k3_final(
    const float* __restrict__ dsim, const float* __restrict__ row_sum,
    const float* __restrict__ wp, const float* __restrict__ bp,
    float* __restrict__ out)
{
  const int r = blockIdx.x * 256 + threadIdx.x;   // 128 blocks -> 32768 rows
  const float w = wp[0], b = bp[0];
  const float B = fabsf(w) + fabsf(b);
  float v = -fmaf(w, dsim[r], b) + B + logf(row_sum[r]);
  #pragma unroll
  for (int off = 32; off; off >>= 1) v += __shfl_xor(v, off, 64);
  __shared__ float red[4];
  const int lane = threadIdx.x & 63, wv = threadIdx.x >> 6;
  if (lane == 0) red[wv] = v;
  __syncthreads();
  if (threadIdx.x == 0) atomicAdd(out, red[0] + red[1] + red[2] + red[3]);
}

// ---------------------------------------------------------------------------
extern "C" void kernel_launch(void* const* d_in, const int* in_sizes, int n_in,
                              void* d_out, int out_size, void* d_ws, size_t ws_size,
                              hipStream_t stream)
{
  const float* x = (const float*)d_in[0];
  const float* w = (const float*)d_in[1];
  const float* b = (const float*)d_in[2];
  float* out = (float*)d_out;
  float* ws = (float*)d_ws;

  float* cent_t = ws;                    // 256*1024 = 262144 floats (1 MiB)
  float* cn     = ws + 262144;           // 1024
  float* xn     = ws + 263168;           // 32768
  float* dsim   = ws + 295936;           // 32768
  float* rowsum = ws + 328704;           // 32768   (total ~1.41 MB)

  hipMemsetAsync(rowsum, 0, 32768 * sizeof(float), stream);
  hipMemsetAsync(out, 0, sizeof(float), stream);

  k1_prep<<<1024, 256, 0, stream>>>(x, cent_t, cn, xn, dsim);
  k2_gemm_lse<<<4096, 256, 0, stream>>>(x, cent_t, cn, xn, dsim, w, b, rowsum);
  k3_final<<<128, 256, 0, stream>>>(dsim, rowsum, w, b, out);
}

// Round 6
// 200.034 us; speedup vs baseline: 1.6508x; 1.6508x over previous
//
#include <hip/hip_runtime.h>
#include <hip/hip_bf16.h>
#include <math.h>

typedef float f32x4 __attribute__((ext_vector_type(4)));
typedef short short8 __attribute__((ext_vector_type(8)));

#define GEPS 1e-6f

static __device__ __forceinline__ short8 ldb8(const __hip_bfloat16* p) {
  return *reinterpret_cast<const short8*>(p);
}

// ---------------------------------------------------------------------------
// Kernel 1: per-speaker prep. block n (1024 blocks, 256 thr).
//   x_hi/x_lo : bf16 hi/lo split of x, row-major [32768][256]
//   c_hi/c_lo : bf16 hi/lo split of centroids, row-major [1024][256]
//   invcn[n]  = 1/||cent_n||   (eps clamp unnecessary: gaussian norms ~2.8)
//   xn[n,m]   = ||x_{n,m}||
//   dsim[n,m] = cos-sim(x, mod_cent) with eps clamp (matches reference)
// ---------------------------------------------------------------------------
__global__ __launch_bounds__(256) void k1_prep(
    const float* __restrict__ x,
    __hip_bfloat16* __restrict__ xhg, __hip_bfloat16* __restrict__ xlg,
    __hip_bfloat16* __restrict__ chg, __hip_bfloat16* __restrict__ clg,
    float* __restrict__ invcn, float* __restrict__ xn, float* __restrict__ dsim)
{
  const int n = blockIdx.x;
  const int tid = threadIdx.x;
  const int lane = tid & 63;
  const int wv = tid >> 6;
  __shared__ float xsh[32 * 256];
  __shared__ float sl[256];
  __shared__ float red[4];

  const float* xg = x + (size_t)n * 8192;
  float s = 0.f;
  #pragma unroll
  for (int m = 0; m < 32; ++m) {
    float v = xg[m * 256 + tid];
    xsh[m * 256 + tid] = v;
    s += v;
    __hip_bfloat16 h = __float2bfloat16(v);
    float hf = __bfloat162float(h);
    xhg[(size_t)n * 8192 + m * 256 + tid] = h;
    xlg[(size_t)n * 8192 + m * 256 + tid] = __float2bfloat16(v - hf);
  }
  sl[tid] = s;
  const float c = s * 0.03125f;              // centroid element (exact /32)
  {
    __hip_bfloat16 h = __float2bfloat16(c);
    float hf = __bfloat162float(h);
    chg[n * 256 + tid] = h;
    clg[n * 256 + tid] = __float2bfloat16(c - hf);
  }
  float c2 = c * c;
  #pragma unroll
  for (int off = 32; off; off >>= 1) c2 += __shfl_xor(c2, off, 64);
  if (lane == 0) red[wv] = c2;
  __syncthreads();                           // publishes xsh, sl, red
  if (tid == 0) invcn[n] = 1.0f / sqrtf(red[0] + red[1] + red[2] + red[3]);

  #pragma unroll
  for (int g = 0; g < 8; ++g) {
    const int m = wv + 4 * g;
    float a1 = 0.f, a2 = 0.f, a3 = 0.f;
    #pragma unroll
    for (int e = 0; e < 4; ++e) {
      const int d = lane + 64 * e;
      const float xv = xsh[m * 256 + d];
      const float mo = (sl[d] - xv) / 31.0f;  // mod_cent element
      a1 += xv * xv;
      a2 += xv * mo;
      a3 += mo * mo;
    }
    #pragma unroll
    for (int off = 32; off; off >>= 1) {
      a1 += __shfl_xor(a1, off, 64);
      a2 += __shfl_xor(a2, off, 64);
      a3 += __shfl_xor(a3, off, 64);
    }
    if (lane == 0) {
      const float xnv = sqrtf(a1);
      const float mn  = sqrtf(a3);
      xn[n * 32 + m]   = xnv;
      dsim[n * 32 + m] = a2 / fmaxf(xnv * mn, GEPS);
    }
  }
}

// ---------------------------------------------------------------------------
// Kernel 2: bf16-split MFMA dots + fused fixed-bound LSE + loss.
// 512 blocks x 256 thr. Block owns 64 rows (speakers n0=2*bid, n0+1).
// 4 waves share the rows, split cols: wave wv -> coltiles ct = 2*wv, 2*wv+1
// (128 cols each). No barriers in the main loop; no LDS staging.
// Per wave: acc[4 mt][8 kt] 16x16 tiles, K-loop 8 chunks of 32 d.
// 3 mfma passes per (mt,kt,chunk): al*bh + ah*bl + ah*bh  (lo*lo dropped).
// Frag maps (m89-verified family): A row = lane&15, B col = lane&15,
// k = (lane>>4)*8 + j (same map for A and B => any k-grouping error cancels).
// C/D: col = lane&15, row = (lane>>4)*4 + reg.
// Epilogue: p = exp2(dot * (w*log2e/xn_row) * invcn_col + (b-B)*log2e),
// diag (col==speaker(row)) replaced by exp2 of dsim-based arg. Per-lane
// partials -> 16-lane shfl reduce -> LDS rs[64] -> block loss -> atomicAdd.
// ---------------------------------------------------------------------------
__global__ __launch_bounds__(256, 2) void k2_mfma(
    const __hip_bfloat16* __restrict__ xhg, const __hip_bfloat16* __restrict__ xlg,
    const __hip_bfloat16* __restrict__ chg, const __hip_bfloat16* __restrict__ clg,
    const float* __restrict__ invcn, const float* __restrict__ xn,
    const float* __restrict__ dsim, const float* __restrict__ wp,
    const float* __restrict__ bp, float* __restrict__ out)
{
  const int bid = blockIdx.x;
  const int tid = threadIdx.x;
  const int wv = tid >> 6;
  const int lane = tid & 63;
  const int q = lane >> 4;          // quarter 0..3
  const int l15 = lane & 15;
  const int rowbase = bid * 64;

  __shared__ float rs[64];
  if (tid < 64) rs[tid] = 0.f;
  __syncthreads();

  const float w = wp[0], b = bp[0];
  const float B = fabsf(w) + fabsf(b);
  const float L2E = 1.44269504088896f;
  const float u = (b - B) * L2E;
  const float wl = w * L2E;

  // hoisted per-row constants; row(mt,reg) = rowbase + mt*16 + q*4 + reg
  float srow[4][4], er[4][4];
  #pragma unroll
  for (int mt = 0; mt < 4; ++mt)
    #pragma unroll
    for (int r = 0; r < 4; ++r) {
      const int grow = rowbase + mt * 16 + q * 4 + r;
      srow[mt][r] = wl / xn[grow];
      er[mt][r]   = fmaf(dsim[grow], wl, u);   // diag exp2-arg
    }

  float S[4][4];
  #pragma unroll
  for (int mt = 0; mt < 4; ++mt)
    #pragma unroll
    for (int r = 0; r < 4; ++r) S[mt][r] = 0.f;

  #pragma unroll 1
  for (int ci = 0; ci < 2; ++ci) {
    const int ct = wv * 2 + ci;
    const int colbase = ct * 128;
    f32x4 acc[4][8];
    #pragma unroll
    for (int mt = 0; mt < 4; ++mt)
      #pragma unroll
      for (int kt = 0; kt < 8; ++kt) acc[mt][kt] = (f32x4){0.f, 0.f, 0.f, 0.f};

    #pragma unroll 1
    for (int ck = 0; ck < 8; ++ck) {
      const int d0 = ck * 32 + q * 8;
      short8 a_h[4], a_l[4];
      #pragma unroll
      for (int mt = 0; mt < 4; ++mt) {
        const size_t abase = (size_t)(rowbase + mt * 16 + l15) * 256 + d0;
        a_h[mt] = ldb8(xhg + abase);
        a_l[mt] = ldb8(xlg + abase);
      }
      #pragma unroll
      for (int kt = 0; kt < 8; ++kt) {
        const size_t bbase = (size_t)(colbase + kt * 16 + l15) * 256 + d0;
        const short8 b_h = ldb8(chg + bbase);
        const short8 b_l = ldb8(clg + bbase);
        #pragma unroll
        for (int mt = 0; mt < 4; ++mt) {
          acc[mt][kt] = __builtin_amdgcn_mfma_f32_16x16x32_bf16(a_l[mt], b_h, acc[mt][kt], 0, 0, 0);
          acc[mt][kt] = __builtin_amdgcn_mfma_f32_16x16x32_bf16(a_h[mt], b_l, acc[mt][kt], 0, 0, 0);
          acc[mt][kt] = __builtin_amdgcn_mfma_f32_16x16x32_bf16(a_h[mt], b_h, acc[mt][kt], 0, 0, 0);
        }
      }
    }

    // epilogue for this coltile
    #pragma unroll
    for (int kt = 0; kt < 8; ++kt) {
      const int colg = colbase + kt * 16 + l15;
      const float tc = invcn[colg];
      #pragma unroll
      for (int mt = 0; mt < 4; ++mt) {
        const int nrow = (rowbase + mt * 16) >> 5;   // speaker of this mt
        #pragma unroll
        for (int r = 0; r < 4; ++r) {
          float p = exp2f(fmaf(acc[mt][kt][r] * srow[mt][r], tc, u));
          if (colg == nrow) p = exp2f(er[mt][r]);    // diagonal splice
          S[mt][r] += p;
        }
      }
    }
  }

  // fold per-lane partials into per-row sums (16-lane groups hold 16 cols)
  #pragma unroll
  for (int mt = 0; mt < 4; ++mt)
    #pragma unroll
    for (int r = 0; r < 4; ++r) {
      float v = S[mt][r];
      v += __shfl_xor(v, 1, 64);
      v += __shfl_xor(v, 2, 64);
      v += __shfl_xor(v, 4, 64);
      v += __shfl_xor(v, 8, 64);
      if (l15 == 0) atomicAdd(&rs[mt * 16 + q * 4 + r], v);
    }
  __syncthreads();

  if (tid < 64) {   // wave 0 finishes: loss_row = -(w*dsim+b) + B + ln(rowsum)
    const int grow = rowbase + tid;
    float lr = -fmaf(w, dsim[grow], b) + B + log2f(rs[tid]) * 0.6931471805599453f;
    #pragma unroll
    for (int off = 1; off < 64; off <<= 1) lr += __shfl_xor(lr, off, 64);
    if (tid == 0) atomicAdd(out, lr);
  }
}

// ---------------------------------------------------------------------------
extern "C" void kernel_launch(void* const* d_in, const int* in_sizes, int n_in,
                              void* d_out, int out_size, void* d_ws, size_t ws_size,
                              hipStream_t stream)
{
  const float* x = (const float*)d_in[0];
  const float* w = (const float*)d_in[1];
  const float* b = (const float*)d_in[2];
  float* out = (float*)d_out;

  char* W = (char*)d_ws;
  __hip_bfloat16* xhg = (__hip_bfloat16*)(W);                  // 16 MiB
  __hip_bfloat16* xlg = (__hip_bfloat16*)(W + 16777216);       // 16 MiB
  __hip_bfloat16* chg = (__hip_bfloat16*)(W + 33554432);       // 512 KiB
  __hip_bfloat16* clg = (__hip_bfloat16*)(W + 34078720);       // 512 KiB
  float* invcn = (float*)(W + 34603008);                       // 4 KiB
  float* xn    = (float*)(W + 34607104);                       // 128 KiB
  float* dsim  = (float*)(W + 34738176);                       // 128 KiB
                                                               // total ~33.3 MiB
  hipMemsetAsync(out, 0, sizeof(float), stream);
  k1_prep<<<1024, 256, 0, stream>>>(x, xhg, xlg, chg, clg, invcn, xn, dsim);
  k2_mfma<<<512, 256, 0, stream>>>(xhg, xlg, chg, clg, invcn, xn, dsim, w, b, out);
}